// Round 9
// baseline (24469.585 us; speedup 1.0000x reference)
//
#include <hip/hip_runtime.h>
#include <math.h>

#define B    32
#define EMBD 1024
#define HID  1024
#define G    4096
#define V    32000
#define TS   128
#define XROW (TS + 1)
#define KSL  8      // lstm k-splits (256 k of concat-2048 each)
#define NFCB 250    // fc blocks (128 rows each, full K)

#define FMA4(acc, W_, V_) \
  acc = fmaf((W_).x,(V_).x, fmaf((W_).y,(V_).y, fmaf((W_).z,(V_).z, fmaf((W_).w,(V_).w,(acc)))))

// swizzled LDS slot for staged [64 col][32 b] float4 tile:
// write: consecutive cols spread across bank-quads; read: kq-strided cols
// (col = kq*8+i) land in distinct quads since quad = (b + (col>>3)) & 7.
__device__ __forceinline__ int slt(int col, int b) {
    return col * 32 + ((b + (col >> 3)) & 31);
}

// ---------------- init: states=0, xcur = emb[x[:,0]] ----------------
__global__ __launch_bounds__(256) void k_init(
    const int* __restrict__ x, const float* __restrict__ emb,
    float* __restrict__ xcur, float* __restrict__ st /*4 buffers*/)
{
    const int b = blockIdx.x, tid = threadIdx.x;
    float4 z = {0.f, 0.f, 0.f, 0.f};
#pragma unroll
    for (int q = 0; q < 4; q++)
        ((float4*)(st + (size_t)q * B * HID + (size_t)b * HID))[tid] = z;
    const int tok = x[b * XROW];
    ((float4*)(xcur + (size_t)b * EMBD))[tid] =
        ((const float4*)(emb + (size_t)tok * EMBD))[tid];
}

// ---------------- LSTM gates partial GEMM ----------------
// grid (32 jb, 8 ksb), block 512 = 8 waves = 2 wr x 4 wb.
// Wave: 64 rows x 8 b. Lane (rs 0..7, kq 0..7): J=8 rows, B_t=8 b, 8 f4 k-slice.
__global__ __launch_bounds__(512) void k_layer(
    const float* __restrict__ xin, const float* __restrict__ hin,
    const float* __restrict__ Wih, const float* __restrict__ Whh,
    float* __restrict__ gpart)
{
    __shared__ float4 sbx[2048];            // 32 KB swizzled [64 col][32 b]
    const int tid  = threadIdx.x;
    const int ww   = tid >> 6;
    const int lane = tid & 63;
    const int rs   = lane >> 3;
    const int kq   = lane & 7;
    const int wr   = ww >> 2;               // 0..1
    const int wb   = ww & 3;                // 0..3
    const int jb   = blockIdx.x;            // 0..31
    const int ksb  = blockIdx.y;            // 0..7
    const bool xp  = (ksb < 4);
    const float* __restrict__ src = xp ? xin : hin;
    const float* __restrict__ Wb  = xp ? Wih : Whh;
    const int cb = (ksb & 3) * 64;          // f4 col base within 256-f4 row

    const float4* srcv = (const float4*)src;
#pragma unroll
    for (int e = 0; e < 4; e++) {
        const int fi = tid + e * 512;       // 0..2047
        const int b = fi >> 6, col = fi & 63;
        sbx[slt(col, b)] = srcv[b * 256 + cb + col];
    }
    __syncthreads();

    const int j0 = jb * 128 + wr * 64 + rs * 8;
    const float4* wp0 = (const float4*)Wb + (size_t)j0 * 256 + cb + kq * 8;
    const int b0 = wb * 8;

    float acc[8][8];
#pragma unroll
    for (int jj = 0; jj < 8; jj++)
#pragma unroll
        for (int bl = 0; bl < 8; bl++) acc[jj][bl] = 0.f;

#pragma unroll 2
    for (int i = 0; i < 8; i++) {
        float4 w[8];
#pragma unroll
        for (int jj = 0; jj < 8; jj++) w[jj] = wp0[jj * 256 + i];
        const int cbase = (kq * 8 + i) * 32;
        const int badd  = b0 + kq;
#pragma unroll
        for (int bl = 0; bl < 8; bl++) {
            const float4 xv = sbx[cbase + ((badd + bl) & 31)];
#pragma unroll
            for (int jj = 0; jj < 8; jj++) FMA4(acc[jj][bl], w[jj], xv);
        }
    }

    // kq 8-way reduce
#pragma unroll
    for (int jj = 0; jj < 8; jj++)
#pragma unroll
        for (int bl = 0; bl < 8; bl++) {
            acc[jj][bl] += __shfl_xor(acc[jj][bl], 1);
            acc[jj][bl] += __shfl_xor(acc[jj][bl], 2);
            acc[jj][bl] += __shfl_xor(acc[jj][bl], 4);
        }

    // lane kq writes row jj=kq (static-index select), coalesced over lanes
    const int jw = j0 + kq;
#pragma unroll
    for (int bl = 0; bl < 8; bl++) {
        float v = acc[0][bl];
#pragma unroll
        for (int jj = 1; jj < 8; jj++)
            if (kq == jj) v = acc[jj][bl];
        gpart[((size_t)ksb * B + b0 + bl) * G + jw] = v;
    }
}

// ---------------- reduce gate partials + activations + state ----------------
// grid 128, block 256; idx = b*1024 + jh
__global__ __launch_bounds__(256) void k_act(
    const float* __restrict__ part, const float* __restrict__ bih,
    const float* __restrict__ bhh, float* __restrict__ c, float* __restrict__ h)
{
    const int idx = blockIdx.x * 256 + threadIdx.x;
    const int b = idx >> 10, jh = idx & 1023;
    float gi = bih[jh]        + bhh[jh];
    float gf = bih[jh + 1024] + bhh[jh + 1024];
    float gg = bih[jh + 2048] + bhh[jh + 2048];
    float go = bih[jh + 3072] + bhh[jh + 3072];
#pragma unroll
    for (int ks = 0; ks < KSL; ks++) {
        const float* p = part + ((size_t)ks * B + b) * G;
        gi += p[jh]; gf += p[jh + 1024]; gg += p[jh + 2048]; go += p[jh + 3072];
    }
    const float i = 1.f / (1.f + expf(-gi));
    const float f = 1.f / (1.f + expf(-gf));
    const float g = tanhf(gg);
    const float o = 1.f / (1.f + expf(-go));
    const float cn = f * c[idx] + i * g;
    c[idx] = cn;
    h[idx] = o * tanhf(cn);
}

// ---------------- fused FC: full-K GEMM + bias + softmax partials ----------
// grid 250, block 512 = 8 waves = 2 wr x 4 wb; block = 128 rows x 32 b.
__global__ __launch_bounds__(512) void k_fc(
    const float* __restrict__ h1, const float* __restrict__ W,
    const float* __restrict__ bfc, const int* __restrict__ x, int t,
    float* __restrict__ psum, float* __restrict__ pmax, int* __restrict__ pidx,
    float* __restrict__ lt)
{
    __shared__ float4 sbx[2048];            // 32 KB stage; logits overlay later
    __shared__ float segS[16 * 32], segM[16 * 32];
    __shared__ int   segI[16 * 32];
    float* logits = (float*)sbx;            // [128][33] padded

    const int tid  = threadIdx.x;
    const int ww   = tid >> 6;
    const int lane = tid & 63;
    const int rs   = lane >> 3;
    const int kq   = lane & 7;
    const int wr   = ww >> 2;
    const int wb   = ww & 3;
    const int jb   = blockIdx.x;            // 0..249
    const int j0   = jb * 128 + wr * 64 + rs * 8;
    const int b0   = wb * 8;

    const float4* wp0 = (const float4*)W + (size_t)j0 * 256 + kq * 8;
    const float4* h1v = (const float4*)h1;  // [32][256]

    float acc[8][8];
#pragma unroll
    for (int jj = 0; jj < 8; jj++)
#pragma unroll
        for (int bl = 0; bl < 8; bl++) acc[jj][bl] = 0.f;

    for (int cch = 0; cch < 4; cch++) {
        __syncthreads();
#pragma unroll
        for (int e = 0; e < 4; e++) {
            const int fi = tid + e * 512;
            const int b = fi >> 6, col = fi & 63;
            sbx[slt(col, b)] = h1v[b * 256 + cch * 64 + col];
        }
        __syncthreads();
#pragma unroll 2
        for (int i = 0; i < 8; i++) {
            float4 w[8];
#pragma unroll
            for (int jj = 0; jj < 8; jj++)
                w[jj] = wp0[jj * 256 + cch * 64 + i];
            const int cbase = (kq * 8 + i) * 32;
            const int badd  = b0 + kq;
#pragma unroll
            for (int bl = 0; bl < 8; bl++) {
                const float4 xv = sbx[cbase + ((badd + bl) & 31)];
#pragma unroll
                for (int jj = 0; jj < 8; jj++) FMA4(acc[jj][bl], w[jj], xv);
            }
        }
    }

    // kq 8-way reduce
#pragma unroll
    for (int jj = 0; jj < 8; jj++)
#pragma unroll
        for (int bl = 0; bl < 8; bl++) {
            acc[jj][bl] += __shfl_xor(acc[jj][bl], 1);
            acc[jj][bl] += __shfl_xor(acc[jj][bl], 2);
            acc[jj][bl] += __shfl_xor(acc[jj][bl], 4);
        }
    __syncthreads();   // stage no longer needed; reuse as logits

    // lane kq owns row rw = wr*64+rs*8+kq; bias + store to logits
    {
        const int rw = wr * 64 + rs * 8 + kq;
        const float bv = bfc[jb * 128 + rw];
#pragma unroll
        for (int bl = 0; bl < 8; bl++) {
            float v = acc[0][bl];
#pragma unroll
            for (int jj = 1; jj < 8; jj++)
                if (kq == jj) v = acc[jj][bl];
            logits[rw * 33 + b0 + bl] = v + bv;
        }
    }
    __syncthreads();

    // softmax/argmax partials: 512 thr = 32 b x 16 segs of 8 rows
    {
        const int b = tid & 31, seg = tid >> 5;
        float ls = 0.f, lm = -1e30f; int li = 0;
#pragma unroll
        for (int i = 0; i < 8; i++) {
            const int rw = seg * 8 + i;
            const float l = logits[rw * 33 + b];
            ls += expf(l);
            if (l > lm) { lm = l; li = rw; }
        }
        segS[seg * 32 + b] = ls; segM[seg * 32 + b] = lm; segI[seg * 32 + b] = li;
    }
    __syncthreads();
    if (tid < 32) {
        const int b = tid;
        float ts = 0.f, tm = -1e30f; int ti = 0;
#pragma unroll
        for (int seg = 0; seg < 16; seg++) {
            ts += segS[seg * 32 + b];
            const float mv = segM[seg * 32 + b]; const int ix = segI[seg * 32 + b];
            if (mv > tm) { tm = mv; ti = ix; }
        }
        psum[b * NFCB + jb] = ts;
        pmax[b * NFCB + jb] = tm;
        pidx[b * NFCB + jb] = jb * 128 + ti;
        const int tgt = x[b * XROW + t + 1];
        const int loc = tgt - jb * 128;
        if (loc >= 0 && loc < 128) lt[b] = logits[loc * 33 + b];
    }
}

// ---------------- finalize: p(target), argmax -> xcur = emb[pred] ----------
// grid 32 (b), block 256
__global__ __launch_bounds__(256) void k_fin(
    const float* __restrict__ psum, const float* __restrict__ pmax,
    const int* __restrict__ pidx, const float* __restrict__ lt,
    const float* __restrict__ emb, float* __restrict__ xcur,
    float* __restrict__ out, int t)
{
    const int b = blockIdx.x, tid = threadIdx.x;
    __shared__ float ss[256], sm[256];
    __shared__ int si[256];
    __shared__ int s_pred;
    const bool v = (tid < NFCB);
    ss[tid] = v ? psum[b * NFCB + tid] : 0.f;
    sm[tid] = v ? pmax[b * NFCB + tid] : -1e30f;
    si[tid] = v ? pidx[b * NFCB + tid] : 0x7fffffff;
    __syncthreads();
    for (int s = 128; s > 0; s >>= 1) {
        if (tid < s) {
            ss[tid] += ss[tid + s];
            const float mv = sm[tid + s]; const int ix = si[tid + s];
            if (mv > sm[tid] || (mv == sm[tid] && ix < si[tid])) {
                sm[tid] = mv; si[tid] = ix;
            }
        }
        __syncthreads();
    }
    if (tid == 0) {
        out[(size_t)b * TS + t] = expf(lt[b]) / ss[0];
        s_pred = si[0];
    }
    __syncthreads();
    ((float4*)(xcur + (size_t)b * EMBD))[tid] =
        ((const float4*)(emb + (size_t)s_pred * EMBD))[tid];
}

extern "C" void kernel_launch(void* const* d_in, const int* in_sizes, int n_in,
                              void* d_out, int out_size, void* d_ws, size_t ws_size,
                              hipStream_t stream)
{
    const int*   x   = (const int*)  d_in[0];
    const float* emb = (const float*)d_in[1];
    const float* Wih = (const float*)d_in[2];
    const float* Whh = (const float*)d_in[3];
    const float* bih = (const float*)d_in[4];
    const float* bhh = (const float*)d_in[5];
    const float* Wfc = (const float*)d_in[6];
    const float* bfc = (const float*)d_in[7];
    float* out = (float*)d_out;

    const size_t SB = (size_t)B * HID;
    float* ws = (float*)d_ws;
    float* xcur = ws;                        // B*EMBD
    float* st   = xcur + (size_t)B * EMBD;   // h0,h1,c0,c1
    float* h0 = st, *h1 = st + SB, *c0 = st + 2 * SB, *c1 = st + 3 * SB;
    float* gpart = st + 4 * SB;              // KSL*B*G
    float* psum  = gpart + (size_t)KSL * B * G;
    float* pmax  = psum + B * NFCB;
    float* lt    = pmax + B * NFCB;          // B
    int*   pidx  = (int*)(lt + B);           // B*NFCB

    const size_t G4 = (size_t)G;

    k_init<<<B, 256, 0, stream>>>(x, emb, xcur, st);

    for (int t = 0; t < TS; t++) {
        k_layer<<<dim3(32, KSL), 512, 0, stream>>>(xcur, h0, Wih, Whh, gpart);
        k_act<<<128, 256, 0, stream>>>(gpart, bih, bhh, c0, h0);
        k_layer<<<dim3(32, KSL), 512, 0, stream>>>(h0, h1, Wih + G4 * EMBD,
                                                   Whh + G4 * HID, gpart);
        k_act<<<128, 256, 0, stream>>>(gpart, bih + G, bhh + G, c1, h1);
        k_fc<<<NFCB, 512, 0, stream>>>(h1, Wfc, bfc, x, t, psum, pmax, pidx, lt);
        k_fin<<<B, 256, 0, stream>>>(psum, pmax, pidx, lt, emb, xcur, out, t);
    }
}

// Round 10
// 10743.064 us; speedup vs baseline: 2.2777x; 2.2777x over previous
//
#include <hip/hip_runtime.h>
#include <math.h>

#define B    32
#define EMBD 1024
#define HID  1024
#define G    4096
#define V    32000
#define TS   128
#define XROW (TS + 1)
#define KSL  8      // lstm k-splits (chunk 256 of concat-2048)
#define NFCB 250    // fc blocks (128 rows each, full K)

#define FMA4(acc, W_, V_) \
  acc = fmaf((W_).x,(V_).x, fmaf((W_).y,(V_).y, fmaf((W_).z,(V_).z, fmaf((W_).w,(V_).w,(acc)))))

// ---------------- init: states=0, xcur = emb[x[:,0]] ----------------
__global__ __launch_bounds__(256) void k_init(
    const int* __restrict__ x, const float* __restrict__ emb,
    float* __restrict__ xcur, float* __restrict__ st /*4 buffers*/)
{
    const int b = blockIdx.x, tid = threadIdx.x;
    float4 z = {0.f, 0.f, 0.f, 0.f};
#pragma unroll
    for (int q = 0; q < 4; q++)
        ((float4*)(st + (size_t)q * B * HID + (size_t)b * HID))[tid] = z;
    const int tok = x[b * XROW];
    ((float4*)(xcur + (size_t)b * EMBD))[tid] =
        ((const float4*)(emb + (size_t)tok * EMBD))[tid];
}

// ---------------- LSTM gates partial GEMM: R8-proven, unchanged --------------
// grid (32 jb, 8 ks), block 512 = 8 waves (batch-split). Wave: 128 rows, 4 b.
// Lane (rs 0..15, kq 0..3): J=8 rows, B_t=4, kq quarter of 64-f4 chunk.
__global__ __launch_bounds__(512) void k_layer(
    const float* __restrict__ xin, const float* __restrict__ hin,
    const float* __restrict__ Wih, const float* __restrict__ Whh,
    float* __restrict__ gpart)
{
    __shared__ float4 sb4x[2048];           // 32 KB [32 b][64 f4]
    const int tid = threadIdx.x;
    const int ww  = tid >> 6;               // 0..7
    const int lane = tid & 63;
    const int rs  = lane >> 2;              // 0..15
    const int kq  = lane & 3;               // 0..3
    const int jb  = blockIdx.x;             // 0..31
    const int ks  = blockIdx.y;             // 0..7
    const bool xpart = (ks < 4);
    const float* __restrict__ src = xpart ? xin : hin;
    const float* __restrict__ Wb  = xpart ? Wih : Whh;
    const int cchunk = (ks & 3) * 64;       // f4 col base within 256-f4 row

#pragma unroll
    for (int e = 0; e < 4; e++) {
        const int fi = tid + e * 512;
        const int b = fi >> 6, off = fi & 63;
        sb4x[fi] = ((const float4*)(src + (size_t)b * 1024))[cchunk + off];
    }
    __syncthreads();

    const int j0 = jb * 128;
    const float4* W4 = (const float4*)Wb;
    const float4* wp[8];
#pragma unroll
    for (int jj = 0; jj < 8; jj++)
        wp[jj] = W4 + (size_t)(j0 + rs * 8 + jj) * 256 + cchunk;

    float acc[8][4];
#pragma unroll
    for (int jj = 0; jj < 8; jj++)
#pragma unroll
        for (int bl = 0; bl < 4; bl++) acc[jj][bl] = 0.f;

#pragma unroll 4
    for (int s = 0; s < 16; s++) {
        const int col = s * 4 + kq;
        float4 w[8];
#pragma unroll
        for (int jj = 0; jj < 8; jj++) w[jj] = wp[jj][col];
#pragma unroll
        for (int bl = 0; bl < 4; bl++) {
            const float4 xv = sb4x[(ww * 4 + bl) * 64 + col];
#pragma unroll
            for (int jj = 0; jj < 8; jj++) FMA4(acc[jj][bl], w[jj], xv);
        }
    }

    // kq 4-way reduce
#pragma unroll
    for (int jj = 0; jj < 8; jj++)
#pragma unroll
        for (int bl = 0; bl < 4; bl++) {
            acc[jj][bl] += __shfl_xor(acc[jj][bl], 1);
            acc[jj][bl] += __shfl_xor(acc[jj][bl], 2);
        }

    // lane (rs,kq) writes jj = 2kq, 2kq+1
#pragma unroll
    for (int q = 0; q < 2; q++) {
        const int jjw = 2 * kq + q;
        const int r = j0 + rs * 8 + jjw;
#pragma unroll
        for (int bl = 0; bl < 4; bl++) {
            const int b = ww * 4 + bl;
            float v = acc[0][bl];
#pragma unroll
            for (int jj = 1; jj < 8; jj++)
                if (jjw == jj) v = acc[jj][bl];
            gpart[((size_t)ks * B + b) * G + r] = v;
        }
    }
}

// ---------------- reduce gate partials + activations + state ----------------
__global__ __launch_bounds__(256) void k_act(
    const float* __restrict__ part, const float* __restrict__ bih,
    const float* __restrict__ bhh, float* __restrict__ c, float* __restrict__ h)
{
    const int idx = blockIdx.x * 256 + threadIdx.x;
    const int b = idx >> 10, jh = idx & 1023;
    float gi = bih[jh]        + bhh[jh];
    float gf = bih[jh + 1024] + bhh[jh + 1024];
    float gg = bih[jh + 2048] + bhh[jh + 2048];
    float go = bih[jh + 3072] + bhh[jh + 3072];
#pragma unroll
    for (int ks = 0; ks < KSL; ks++) {
        const float* p = part + ((size_t)ks * B + b) * G;
        gi += p[jh]; gf += p[jh + 1024]; gg += p[jh + 2048]; go += p[jh + 3072];
    }
    const float i = 1.f / (1.f + expf(-gi));
    const float f = 1.f / (1.f + expf(-gf));
    const float g = tanhf(gg);
    const float o = 1.f / (1.f + expf(-go));
    const float cn = f * c[idx] + i * g;
    c[idx] = cn;
    h[idx] = o * tanhf(cn);
}

// ---------------- fused FC: full-K GEMM + bias + softmax partials ----------
// grid 250, block 512 = 8 waves = 2 row-groups (wr) x 4 batch-groups (wb).
// Wave: 64 rows x 8 b. Lane (rs 0..15, kq 0..3): J=4 rows, B_t=8.
__global__ __launch_bounds__(512) void k_fc(
    const float* __restrict__ h1, const float* __restrict__ W,
    const float* __restrict__ bfc, const int* __restrict__ x, int t,
    float* __restrict__ psum, float* __restrict__ pmax, int* __restrict__ pidx,
    float* __restrict__ lt)
{
    __shared__ float4 sb4[2048];            // 32 KB stage; logits overlay later
    __shared__ float segS[16 * 32], segM[16 * 32];
    __shared__ int   segI[16 * 32];
    float* logits = (float*)sb4;            // [128][33] padded

    const int tid = threadIdx.x;
    const int ww  = tid >> 6;
    const int lane = tid & 63;
    const int rs  = lane >> 2;              // 0..15
    const int kq  = lane & 3;               // 0..3
    const int wr  = ww >> 2;                // 0..1 row-group
    const int wb  = ww & 3;                 // 0..3 batch-group
    const int jb  = blockIdx.x;             // 0..249
    const int j0  = jb * 128 + wr * 64 + rs * 4;
    const int b0  = wb * 8;

    const float4* W4 = (const float4*)W;
    const float4* wp[4];
#pragma unroll
    for (int jj = 0; jj < 4; jj++)
        wp[jj] = W4 + (size_t)(j0 + jj) * 256;

    float acc[4][8];
#pragma unroll
    for (int jj = 0; jj < 4; jj++)
#pragma unroll
        for (int bl = 0; bl < 8; bl++) acc[jj][bl] = 0.f;

    const float4* h1v = (const float4*)h1;  // [32][256]
    for (int cch = 0; cch < 4; cch++) {
        __syncthreads();
#pragma unroll
        for (int e = 0; e < 4; e++) {
            const int fi = tid + e * 512;
            const int b = fi >> 6, off = fi & 63;
            sb4[fi] = h1v[b * 256 + cch * 64 + off];
        }
        __syncthreads();
#pragma unroll 2
        for (int s = 0; s < 16; s++) {
            const int col = s * 4 + kq;
            float4 w[4];
#pragma unroll
            for (int jj = 0; jj < 4; jj++) w[jj] = wp[jj][cch * 64 + col];
#pragma unroll
            for (int bl = 0; bl < 8; bl++) {
                const float4 xv = sb4[(b0 + bl) * 64 + col];
#pragma unroll
                for (int jj = 0; jj < 4; jj++) FMA4(acc[jj][bl], w[jj], xv);
            }
        }
    }

    // kq 4-way reduce
#pragma unroll
    for (int jj = 0; jj < 4; jj++)
#pragma unroll
        for (int bl = 0; bl < 8; bl++) {
            acc[jj][bl] += __shfl_xor(acc[jj][bl], 1);
            acc[jj][bl] += __shfl_xor(acc[jj][bl], 2);
        }
    __syncthreads();   // stage no longer needed; reuse as logits

    // lane kq owns row rw = wr*64 + rs*4 + kq; bias + store to logits
    {
        const int rw = wr * 64 + rs * 4 + kq;
        const float bv = bfc[jb * 128 + rw];
#pragma unroll
        for (int bl = 0; bl < 8; bl++) {
            float v = acc[0][bl];
#pragma unroll
            for (int jj = 1; jj < 4; jj++)
                if (kq == jj) v = acc[jj][bl];
            logits[rw * 33 + b0 + bl] = v + bv;
        }
    }
    __syncthreads();

    // softmax/argmax partials: 512 thr = 32 b x 16 segs of 8 rows
    {
        const int b = tid & 31, seg = tid >> 5;
        float ls = 0.f, lm = -1e30f; int li = 0;
#pragma unroll
        for (int i = 0; i < 8; i++) {
            const int rw = seg * 8 + i;
            const float l = logits[rw * 33 + b];
            ls += expf(l);
            if (l > lm) { lm = l; li = rw; }
        }
        segS[seg * 32 + b] = ls; segM[seg * 32 + b] = lm; segI[seg * 32 + b] = li;
    }
    __syncthreads();
    if (tid < 32) {
        const int b = tid;
        float ts = 0.f, tm = -1e30f; int ti = 0;
#pragma unroll
        for (int seg = 0; seg < 16; seg++) {
            ts += segS[seg * 32 + b];
            const float mv = segM[seg * 32 + b]; const int ix = segI[seg * 32 + b];
            if (mv > tm) { tm = mv; ti = ix; }
        }
        psum[b * NFCB + jb] = ts;
        pmax[b * NFCB + jb] = tm;
        pidx[b * NFCB + jb] = jb * 128 + ti;
        const int tgt = x[b * XROW + t + 1];
        const int loc = tgt - jb * 128;
        if (loc >= 0 && loc < 128) lt[b] = logits[loc * 33 + b];
    }
}

// ---------------- finalize: p(target), argmax -> xcur = emb[pred] ----------
__global__ __launch_bounds__(256) void k_fin(
    const float* __restrict__ psum, const float* __restrict__ pmax,
    const int* __restrict__ pidx, const float* __restrict__ lt,
    const float* __restrict__ emb, float* __restrict__ xcur,
    float* __restrict__ out, int t)
{
    const int b = blockIdx.x, tid = threadIdx.x;
    __shared__ float ss[256], sm[256];
    __shared__ int si[256];
    __shared__ int s_pred;
    const bool v = (tid < NFCB);
    ss[tid] = v ? psum[b * NFCB + tid] : 0.f;
    sm[tid] = v ? pmax[b * NFCB + tid] : -1e30f;
    si[tid] = v ? pidx[b * NFCB + tid] : 0x7fffffff;
    __syncthreads();
    for (int s = 128; s > 0; s >>= 1) {
        if (tid < s) {
            ss[tid] += ss[tid + s];
            const float mv = sm[tid + s]; const int ix = si[tid + s];
            if (mv > sm[tid] || (mv == sm[tid] && ix < si[tid])) {
                sm[tid] = mv; si[tid] = ix;
            }
        }
        __syncthreads();
    }
    if (tid == 0) {
        out[(size_t)b * TS + t] = expf(lt[b]) / ss[0];
        s_pred = si[0];
    }
    __syncthreads();
    ((float4*)(xcur + (size_t)b * EMBD))[tid] =
        ((const float4*)(emb + (size_t)s_pred * EMBD))[tid];
}

extern "C" void kernel_launch(void* const* d_in, const int* in_sizes, int n_in,
                              void* d_out, int out_size, void* d_ws, size_t ws_size,
                              hipStream_t stream)
{
    const int*   x   = (const int*)  d_in[0];
    const float* emb = (const float*)d_in[1];
    const float* Wih = (const float*)d_in[2];
    const float* Whh = (const float*)d_in[3];
    const float* bih = (const float*)d_in[4];
    const float* bhh = (const float*)d_in[5];
    const float* Wfc = (const float*)d_in[6];
    const float* bfc = (const float*)d_in[7];
    float* out = (float*)d_out;

    const size_t SB = (size_t)B * HID;
    float* ws = (float*)d_ws;
    float* xcur = ws;                        // B*EMBD
    float* st   = xcur + (size_t)B * EMBD;   // h0,h1,c0,c1
    float* h0 = st, *h1 = st + SB, *c0 = st + 2 * SB, *c1 = st + 3 * SB;
    float* gpart = st + 4 * SB;              // KSL*B*G
    float* psum  = gpart + (size_t)KSL * B * G;
    float* pmax  = psum + B * NFCB;
    float* lt    = pmax + B * NFCB;          // B
    int*   pidx  = (int*)(lt + B);           // B*NFCB

    const size_t G4 = (size_t)G;

    k_init<<<B, 256, 0, stream>>>(x, emb, xcur, st);

    for (int t = 0; t < TS; t++) {
        k_layer<<<dim3(32, KSL), 512, 0, stream>>>(xcur, h0, Wih, Whh, gpart);
        k_act<<<128, 256, 0, stream>>>(gpart, bih, bhh, c0, h0);
        k_layer<<<dim3(32, KSL), 512, 0, stream>>>(h0, h1, Wih + G4 * EMBD,
                                                   Whh + G4 * HID, gpart);
        k_act<<<128, 256, 0, stream>>>(gpart, bih + G, bhh + G, c1, h1);
        k_fc<<<NFCB, 512, 0, stream>>>(h1, Wfc, bfc, x, t, psum, pmax, pidx, lt);
        k_fin<<<B, 256, 0, stream>>>(psum, pmax, pidx, lt, emb, xcur, out, t);
    }
}